// Round 1
// baseline (835.959 us; speedup 1.0000x reference)
//
#include <hip/hip_runtime.h>

#define DEV static __device__ __forceinline__

typedef unsigned short u16;
typedef __attribute__((ext_vector_type(8))) short bf16x8;     // 8 bf16 in 4 VGPRs
typedef __attribute__((ext_vector_type(8))) unsigned short u16x8;
typedef __attribute__((ext_vector_type(4))) unsigned short u16x4;
typedef __attribute__((ext_vector_type(4))) float f32x4;

static constexpr int Bb = 4, Ss = 2048, Dd = 1024, Hh = 16, DFF = 4096;
static constexpr int BS = Bb * Ss;  // 8192 rows

DEV u16 f2bf(float f) {
  union { float f; unsigned u; } x; x.f = f;
  unsigned r = x.u + 0x7fffu + ((x.u >> 16) & 1u);  // RNE
  return (u16)(r >> 16);
}

DEV void gload_lds16(const void* g, void* l) {
  __builtin_amdgcn_global_load_lds(
      (const __attribute__((address_space(1))) unsigned int*)g,
      (__attribute__((address_space(3))) unsigned int*)l, 16, 0, 0);
}

DEV f32x4 mfma16(bf16x8 a, bf16x8 b, f32x4 c) {
  return __builtin_amdgcn_mfma_f32_16x16x32_bf16(a, b, c, 0, 0, 0);
}

// ---------------- elementwise cast fp32 -> bf16 ----------------
__global__ void cast_src_k(const float* __restrict__ in, u16* __restrict__ outp, int n) {
  int i = (blockIdx.x * 256 + threadIdx.x) * 4;
  const int stride = gridDim.x * 256 * 4;
  for (; i < n; i += stride) {
    float4 v = *(const float4*)(in + i);
    u16x4 o; o[0] = f2bf(v.x); o[1] = f2bf(v.y); o[2] = f2bf(v.z); o[3] = f2bf(v.w);
    *(u16x4*)(outp + i) = o;
  }
}

// ---------------- transpose + cast: W (KxN f32) -> Wt (NxK bf16) ----------------
__global__ __launch_bounds__(256) void transpose_cast(const float* __restrict__ W,
                                                      u16* __restrict__ Wt, int K, int N) {
  __shared__ float t[32][33];
  const int n0 = blockIdx.x * 32, k0 = blockIdx.y * 32;
  const int tx = threadIdx.x & 31, ty = threadIdx.x >> 5;
#pragma unroll
  for (int i = 0; i < 4; i++) t[ty + i * 8][tx] = W[(size_t)(k0 + ty + i * 8) * N + n0 + tx];
  __syncthreads();
#pragma unroll
  for (int i = 0; i < 4; i++) Wt[(size_t)(n0 + ty + i * 8) * K + k0 + tx] = f2bf(t[tx][ty + i * 8]);
}

// ---------------- mask summary: flags[b]=1 iff mask[b,:,:] all nonzero ----------------
__global__ void mask_init_k(int* flags) { if (threadIdx.x < 4) flags[threadIdx.x] = 1; }
__global__ void mask_check_k(const int* __restrict__ mask, int* __restrict__ flags, int n) {
  int i = blockIdx.x * 256 + threadIdx.x;
  const int st = gridDim.x * 256;
  for (; i < n; i += st) if (mask[i] == 0) flags[i >> 22] = 0;  // S*S = 2^22
}

// ---------------- GEMM: C(MxN) = A(MxK, bf16) * Bt(NxK, bf16)^T ----------------
// MODE 0: f32 out; MODE 1: bf16 out; MODE 2: bf16 out, +bias, relu
template <int MODE>
__global__ __launch_bounds__(256, 2) void gemm_bt(const u16* __restrict__ A,
                                                  const u16* __restrict__ Bt,
                                                  const float* __restrict__ bias,
                                                  void* __restrict__ C,
                                                  int M, int N, int K) {
  __shared__ alignas(16) u16 As[128 * 32];
  __shared__ alignas(16) u16 Bs[128 * 32];
  const int tid = threadIdx.x;
  const int lane = tid & 63;
  const int w = tid >> 6;
  const int wr = (w >> 1) * 64;
  const int wc = (w & 1) * 64;
  const int bm = blockIdx.y * 128;
  const int bn = blockIdx.x * 128;
  const int frow = lane & 15, fk = (lane >> 4) * 8;

  // staging: idx = issue*256+tid covers LDS element idx*8 (linear; matches
  // global_load_lds dest = wave-uniform base + lane*16)
  const int r0 = tid, r1 = 256 + tid;
  const u16* Ag0 = A + (size_t)(bm + (r0 >> 2)) * K + (r0 & 3) * 8;
  const u16* Ag1 = A + (size_t)(bm + (r1 >> 2)) * K + (r1 & 3) * 8;
  const u16* Bg0 = Bt + (size_t)(bn + (r0 >> 2)) * K + (r0 & 3) * 8;
  const u16* Bg1 = Bt + (size_t)(bn + (r1 >> 2)) * K + (r1 & 3) * 8;
  u16* As0 = As + (size_t)(w * 64) * 8;
  u16* As1 = As + (size_t)(256 + w * 64) * 8;
  u16* Bs0 = Bs + (size_t)(w * 64) * 8;
  u16* Bs1 = Bs + (size_t)(256 + w * 64) * 8;

  f32x4 acc[4][4] = {};

  for (int k0 = 0; k0 < K; k0 += 32) {
    gload_lds16(Ag0 + k0, As0);
    gload_lds16(Ag1 + k0, As1);
    gload_lds16(Bg0 + k0, Bs0);
    gload_lds16(Bg1 + k0, Bs1);
    __syncthreads();
    bf16x8 af[4], bfr[4];
#pragma unroll
    for (int m = 0; m < 4; m++) af[m] = *(const bf16x8*)&As[(wr + m * 16 + frow) * 32 + fk];
#pragma unroll
    for (int n = 0; n < 4; n++) bfr[n] = *(const bf16x8*)&Bs[(wc + n * 16 + frow) * 32 + fk];
#pragma unroll
    for (int m = 0; m < 4; m++)
#pragma unroll
      for (int n = 0; n < 4; n++)
        acc[m][n] = mfma16(af[m], bfr[n], acc[m][n]);
    __syncthreads();
  }

#pragma unroll
  for (int m = 0; m < 4; m++) {
#pragma unroll
    for (int n = 0; n < 4; n++) {
      const int col = bn + wc + n * 16 + frow;
      const float bv = (MODE == 2) ? bias[col] : 0.f;
#pragma unroll
      for (int r = 0; r < 4; r++) {
        const int row = bm + wr + m * 16 + (lane >> 4) * 4 + r;  // verified C/D layout
        float v = acc[m][n][r];
        if (MODE == 2) v = fmaxf(v + bv, 0.f);
        if (MODE == 0) ((float*)C)[(size_t)row * N + col] = v;
        else           ((u16*)C)[(size_t)row * N + col] = f2bf(v);
      }
    }
  }
}

// ---------------- fused flash attention ----------------
// qkv: (B*S) x 3072 bf16 rows = [Q(h,dk) | K | V]; out: (B*S) x 1024 bf16
__global__ __launch_bounds__(256, 2) void attn_fwd(const u16* __restrict__ qkv,
                                                   const int* __restrict__ mask,
                                                   const int* __restrict__ mflag,
                                                   u16* __restrict__ outb) {
  __shared__ alignas(16) u16 Ks[2 * 64 * 32];  // [half][kcol][dk%32]
  __shared__ alignas(16) u16 Vt[64 * 72];      // [dk][kcol], pad to 72 (16B-aligned rows, 2-way banks)
  __shared__ alignas(16) u16 Pl[4 * 16 * 72];  // per-wave P tile [qrow][kcol]

  const int bx = blockIdx.x;
  const int qt = bx & 31;
  const int h = (bx >> 5) & 15;
  const int b = bx >> 9;
  const int tid = threadIdx.x;
  const int lane = tid & 63;
  const int w = tid >> 6;
  const int frow = lane & 15, fk = (lane >> 4) * 8;
  const int qbase = qt * 64 + w * 16;

  bf16x8 qf[2];
  {
    const u16* qp = qkv + (size_t)(b * Ss + qbase + frow) * 3072 + h * 64 + fk;
    qf[0] = *(const bf16x8*)(qp);
    qf[1] = *(const bf16x8*)(qp + 32);
  }
  const int allones = mflag[b];
  u16* Plw = Pl + w * (16 * 72);

  f32x4 oacc[4] = {};
  float mrow[4], lrow[4];
#pragma unroll
  for (int r = 0; r < 4; r++) { mrow[r] = -1e30f; lrow[r] = 0.f; }

  const size_t kvb = (size_t)(b * Ss) * 3072 + 1024 + h * 64;  // K block; V at +1024
  // K staging with pre-swizzled global source so LDS is linear [half][kcol][32]
  const int kc0 = tid >> 2, dc0 = (tid & 3) * 8;
  const int vr0 = tid >> 3, vc0 = (tid & 7) * 8;
  u16* Ks0 = Ks + (size_t)(w * 64) * 8;
  u16* Ks1 = Ks + (size_t)(256 + w * 64) * 8;

  for (int kt = 0; kt < 32; kt++) {
    const int srow = kt * 64;
    gload_lds16(qkv + kvb + (size_t)(srow + kc0) * 3072 + dc0, Ks0);
    gload_lds16(qkv + kvb + (size_t)(srow + kc0) * 3072 + 32 + dc0, Ks1);
    u16x8 v0 = *(const u16x8*)(qkv + kvb + 1024 + (size_t)(srow + vr0) * 3072 + vc0);
    u16x8 v1 = *(const u16x8*)(qkv + kvb + 1024 + (size_t)(srow + 32 + vr0) * 3072 + vc0);
#pragma unroll
    for (int j = 0; j < 8; j++) Vt[(vc0 + j) * 72 + vr0] = v0[j];
#pragma unroll
    for (int j = 0; j < 8; j++) Vt[(vc0 + j) * 72 + 32 + vr0] = v1[j];
    __syncthreads();

    // S = Q K^T for this wave's 16 q-rows x 64 k-cols
    f32x4 sacc[4] = {};
#pragma unroll
    for (int ks = 0; ks < 2; ks++)
#pragma unroll
      for (int n = 0; n < 4; n++) {
        bf16x8 kf = *(const bf16x8*)&Ks[ks * 2048 + (n * 16 + frow) * 32 + fk];
        sacc[n] = mfma16(qf[ks], kf, sacc[n]);
      }

    float sv[4][4];
#pragma unroll
    for (int n = 0; n < 4; n++)
#pragma unroll
      for (int r = 0; r < 4; r++) {
        float s = sacc[n][r] * 0.125f;  // 1/sqrt(64)
        if (!allones) {
          const int qq = b * Ss + qbase + (lane >> 4) * 4 + r;
          const int kk = srow + n * 16 + frow;
          if (mask[(size_t)qq * Ss + kk] == 0) s = -1e30f;
        }
        sv[n][r] = s;
      }
    float rmax[4];
#pragma unroll
    for (int r = 0; r < 4; r++)
      rmax[r] = fmaxf(fmaxf(sv[0][r], sv[1][r]), fmaxf(sv[2][r], sv[3][r]));
#pragma unroll
    for (int o = 1; o < 16; o <<= 1)
#pragma unroll
      for (int r = 0; r < 4; r++) rmax[r] = fmaxf(rmax[r], __shfl_xor(rmax[r], o));
    float al[4];
#pragma unroll
    for (int r = 0; r < 4; r++) {
      const float mn = fmaxf(mrow[r], rmax[r]);
      al[r] = __expf(mrow[r] - mn);
      mrow[r] = mn;
    }
    float pf[4][4], rsum[4] = {0.f, 0.f, 0.f, 0.f};
#pragma unroll
    for (int n = 0; n < 4; n++)
#pragma unroll
      for (int r = 0; r < 4; r++) {
        const float p = __expf(sv[n][r] - mrow[r]);
        pf[n][r] = p;
        rsum[r] += p;
      }
#pragma unroll
    for (int o = 1; o < 16; o <<= 1)
#pragma unroll
      for (int r = 0; r < 4; r++) rsum[r] += __shfl_xor(rsum[r], o);
#pragma unroll
    for (int r = 0; r < 4; r++) lrow[r] = lrow[r] * al[r] + rsum[r];
#pragma unroll
    for (int n = 0; n < 4; n++) {
      oacc[n][0] *= al[0]; oacc[n][1] *= al[1];
      oacc[n][2] *= al[2]; oacc[n][3] *= al[3];
    }
#pragma unroll
    for (int n = 0; n < 4; n++)
#pragma unroll
      for (int r = 0; r < 4; r++)
        Plw[((lane >> 4) * 4 + r) * 72 + n * 16 + frow] = f2bf(pf[n][r]);

    // O += P V (wave-local P; compiler inserts lgkmcnt between ds_write/ds_read)
#pragma unroll
    for (int ks = 0; ks < 2; ks++) {
      bf16x8 pa = *(const bf16x8*)&Plw[frow * 72 + ks * 32 + fk];
#pragma unroll
      for (int n = 0; n < 4; n++) {
        bf16x8 vb = *(const bf16x8*)&Vt[(n * 16 + frow) * 72 + ks * 32 + fk];
        oacc[n] = mfma16(pa, vb, oacc[n]);
      }
    }
    __syncthreads();
  }

#pragma unroll
  for (int n = 0; n < 4; n++)
#pragma unroll
    for (int r = 0; r < 4; r++) {
      const int q = qbase + (lane >> 4) * 4 + r;
      const int dk = n * 16 + frow;
      outb[(size_t)(b * Ss + q) * 1024 + h * 64 + dk] = f2bf(oacc[n][r] / lrow[r]);
    }
}

// ---------------- fused residual + bias + LayerNorm ----------------
// s = a + c + bias; y = LN(s)*g + be; writes f32 (of) and/or bf16 (ob)
__global__ __launch_bounds__(256) void ln_fuse(const float* __restrict__ a,
                                               const float* __restrict__ c,
                                               const float* __restrict__ bias,
                                               const float* __restrict__ g,
                                               const float* __restrict__ be,
                                               float* __restrict__ of,
                                               u16* __restrict__ ob) {
  __shared__ float red[4];
  const int tid = threadIdx.x;
  const size_t base = (size_t)blockIdx.x * 1024 + tid * 4;
  float4 va = *(const float4*)(a + base);
  float4 vc = *(const float4*)(c + base);
  float4 vb = *(const float4*)(bias + tid * 4);
  const float s0 = va.x + vc.x + vb.x, s1 = va.y + vc.y + vb.y;
  const float s2 = va.z + vc.z + vb.z, s3 = va.w + vc.w + vb.w;
  float sum = s0 + s1 + s2 + s3;
#pragma unroll
  for (int o = 32; o; o >>= 1) sum += __shfl_xor(sum, o);
  if ((tid & 63) == 0) red[tid >> 6] = sum;
  __syncthreads();
  const float mu = (red[0] + red[1] + red[2] + red[3]) * (1.f / 1024.f);
  __syncthreads();
  const float d0 = s0 - mu, d1 = s1 - mu, d2 = s2 - mu, d3 = s3 - mu;
  float vs = d0 * d0 + d1 * d1 + d2 * d2 + d3 * d3;
#pragma unroll
  for (int o = 32; o; o >>= 1) vs += __shfl_xor(vs, o);
  if ((tid & 63) == 0) red[tid >> 6] = vs;
  __syncthreads();
  const float var = (red[0] + red[1] + red[2] + red[3]) * (1.f / 1024.f);
  const float rs = rsqrtf(var + 1e-5f);
  float4 vg = *(const float4*)(g + tid * 4);
  float4 ve = *(const float4*)(be + tid * 4);
  const float y0 = d0 * rs * vg.x + ve.x, y1 = d1 * rs * vg.y + ve.y;
  const float y2 = d2 * rs * vg.z + ve.z, y3 = d3 * rs * vg.w + ve.w;
  if (of) { float4 y; y.x = y0; y.y = y1; y.z = y2; y.w = y3; *(float4*)(of + base) = y; }
  if (ob) { u16x4 o; o[0] = f2bf(y0); o[1] = f2bf(y1); o[2] = f2bf(y2); o[3] = f2bf(y3);
            *(u16x4*)(ob + base) = o; }
}

extern "C" void kernel_launch(void* const* d_in, const int* in_sizes, int n_in,
                              void* d_out, int out_size, void* d_ws, size_t ws_size,
                              hipStream_t stream) {
  const float* src = (const float*)d_in[0];
  const int* mask = (const int*)d_in[1];
  const float* Wq = (const float*)d_in[2];
  const float* Wk = (const float*)d_in[3];
  const float* Wv = (const float*)d_in[4];
  const float* Wo = (const float*)d_in[5];
  const float* bo = (const float*)d_in[6];
  const float* g1 = (const float*)d_in[7];
  const float* be1 = (const float*)d_in[8];
  const float* W1 = (const float*)d_in[9];
  const float* b1 = (const float*)d_in[10];
  const float* W2 = (const float*)d_in[11];
  const float* b2 = (const float*)d_in[12];
  const float* g2 = (const float*)d_in[13];
  const float* be2 = (const float*)d_in[14];
  float* outp = (float*)d_out;
  (void)in_sizes; (void)n_in; (void)out_size; (void)ws_size;

  char* ws = (char*)d_ws;
  size_t off = 0;
  auto take = [&](size_t bytes) -> char* {
    char* p = ws + off;
    off = (off + bytes + 255) & ~(size_t)255;
    return p;
  };
  u16* srcb  = (u16*)take((size_t)BS * Dd * 2);
  u16* wqkvt = (u16*)take((size_t)3 * Dd * Dd * 2);
  u16* wot   = (u16*)take((size_t)Dd * Dd * 2);
  u16* w1t   = (u16*)take((size_t)Dd * DFF * 2);
  u16* w2t   = (u16*)take((size_t)DFF * Dd * 2);
  char* qkvr = take((size_t)BS * 3 * Dd * 2);  // qkv bf16; later reused as C1/C2 f32
  u16* qkvb  = (u16*)qkvr;
  float* Cf  = (float*)qkvr;
  u16* attnb = (u16*)take((size_t)BS * Dd * 2);  // attn out bf16; later x bf16
  float* xf  = (float*)take((size_t)BS * Dd * 4);
  u16* hb    = (u16*)take((size_t)BS * DFF * 2);
  int* flags = (int*)take(256);

  // prep: casts, weight transposes, mask summary
  cast_src_k<<<2048, 256, 0, stream>>>(src, srcb, BS * Dd);
  transpose_cast<<<dim3(32, 32), 256, 0, stream>>>(Wq, wqkvt,                Dd, Dd);
  transpose_cast<<<dim3(32, 32), 256, 0, stream>>>(Wk, wqkvt + Dd * Dd,      Dd, Dd);
  transpose_cast<<<dim3(32, 32), 256, 0, stream>>>(Wv, wqkvt + 2 * Dd * Dd,  Dd, Dd);
  transpose_cast<<<dim3(32, 32), 256, 0, stream>>>(Wo, wot, Dd, Dd);
  transpose_cast<<<dim3(128, 32), 256, 0, stream>>>(W1, w1t, Dd, DFF);
  transpose_cast<<<dim3(32, 128), 256, 0, stream>>>(W2, w2t, DFF, Dd);
  mask_init_k<<<1, 64, 0, stream>>>(flags);
  mask_check_k<<<2048, 256, 0, stream>>>(mask, flags, Bb * Ss * Ss);

  // QKV projection (fused 3 GEMMs): (8192x1024)x(1024x3072) -> bf16
  gemm_bt<1><<<dim3(3 * Dd / 128, BS / 128), 256, 0, stream>>>(srcb, wqkvt, nullptr, qkvb,
                                                               BS, 3 * Dd, Dd);
  // fused attention
  attn_fwd<<<Bb * Hh * (Ss / 64), 256, 0, stream>>>(qkvb, mask, flags, attnb);
  // out @ Wo -> f32 (bias folded into LN1)
  gemm_bt<0><<<dim3(Dd / 128, BS / 128), 256, 0, stream>>>(attnb, wot, nullptr, Cf,
                                                           BS, Dd, Dd);
  // x = LN(src + attn_out + bo); write bf16 (FFN input) + f32 (residual)
  ln_fuse<<<BS, 256, 0, stream>>>(src, Cf, bo, g1, be1, xf, attnb);
  // h = relu(x @ W1 + b1) -> bf16
  gemm_bt<2><<<dim3(DFF / 128, BS / 128), 256, 0, stream>>>(attnb, w1t, b1, hb,
                                                            BS, DFF, Dd);
  // C2 = h @ W2 -> f32 (b2 folded into LN2)
  gemm_bt<0><<<dim3(Dd / 128, BS / 128), 256, 0, stream>>>(hb, w2t, nullptr, Cf,
                                                           BS, Dd, DFF);
  // out = LN(x + ff + b2)
  ln_fuse<<<BS, 256, 0, stream>>>(xf, Cf, b2, g2, be2, outp, nullptr);
}

// Round 2
// 692.610 us; speedup vs baseline: 1.2070x; 1.2070x over previous
//
#include <hip/hip_runtime.h>

#define DEV static __device__ __forceinline__

typedef unsigned short u16;
typedef __attribute__((ext_vector_type(8))) short bf16x8;     // 8 bf16 in 4 VGPRs
typedef __attribute__((ext_vector_type(8))) unsigned short u16x8;
typedef __attribute__((ext_vector_type(4))) unsigned short u16x4;
typedef __attribute__((ext_vector_type(4))) float f32x4;

static constexpr int Bb = 4, Ss = 2048, Dd = 1024, Hh = 16, DFF = 4096;
static constexpr int BS = Bb * Ss;  // 8192 rows

DEV u16 f2bf(float f) {
  union { float f; unsigned u; } x; x.f = f;
  unsigned r = x.u + 0x7fffu + ((x.u >> 16) & 1u);  // RNE
  return (u16)(r >> 16);
}

DEV void gload_lds16(const void* g, void* l) {
  __builtin_amdgcn_global_load_lds(
      (const __attribute__((address_space(1))) unsigned int*)g,
      (__attribute__((address_space(3))) unsigned int*)l, 16, 0, 0);
}

DEV unsigned lds_addr(const void* p) {
  return (unsigned)(size_t)(const __attribute__((address_space(3))) void*)p;
}

DEV f32x4 mfma16(bf16x8 a, bf16x8 b, f32x4 c) {
  return __builtin_amdgcn_mfma_f32_16x16x32_bf16(a, b, c, 0, 0, 0);
}

DEV bf16x8 cat8(u16x4 a, u16x4 b) {
  bf16x8 v;
#pragma unroll
  for (int j = 0; j < 4; j++) { v[j] = (short)a[j]; v[j + 4] = (short)b[j]; }
  return v;
}

// hardware transpose read: 64b per lane, 16-bit element transpose within 16-lane group
#define TRRD(dst, addr, OFF)                                     \
  asm volatile("ds_read_b64_tr_b16 %0, %1 offset:" #OFF         \
               : "=v"(dst) : "v"(addr))

// ---------------- elementwise cast fp32 -> bf16 ----------------
__global__ void cast_src_k(const float* __restrict__ in, u16* __restrict__ outp, int n) {
  int i = (blockIdx.x * 256 + threadIdx.x) * 4;
  const int stride = gridDim.x * 256 * 4;
  for (; i < n; i += stride) {
    float4 v = *(const float4*)(in + i);
    u16x4 o; o[0] = f2bf(v.x); o[1] = f2bf(v.y); o[2] = f2bf(v.z); o[3] = f2bf(v.w);
    *(u16x4*)(outp + i) = o;
  }
}

// ---------------- transpose + cast: W (KxN f32) -> Wt (NxK bf16) ----------------
__global__ __launch_bounds__(256) void transpose_cast(const float* __restrict__ W,
                                                      u16* __restrict__ Wt, int K, int N) {
  __shared__ float t[32][33];
  const int n0 = blockIdx.x * 32, k0 = blockIdx.y * 32;
  const int tx = threadIdx.x & 31, ty = threadIdx.x >> 5;
#pragma unroll
  for (int i = 0; i < 4; i++) t[ty + i * 8][tx] = W[(size_t)(k0 + ty + i * 8) * N + n0 + tx];
  __syncthreads();
#pragma unroll
  for (int i = 0; i < 4; i++) Wt[(size_t)(n0 + ty + i * 8) * K + k0 + tx] = f2bf(t[tx][ty + i * 8]);
}

// ---------------- mask summary: flags[b]=1 iff mask[b,:,:] all nonzero ----------------
__global__ void mask_init_k(int* flags) { if (threadIdx.x < 4) flags[threadIdx.x] = 1; }
__global__ void mask_check_k(const int* __restrict__ mask, int* __restrict__ flags, int n) {
  int i = blockIdx.x * 256 + threadIdx.x;
  const int st = gridDim.x * 256;
  for (; i < n; i += st) if (mask[i] == 0) flags[i >> 22] = 0;  // S*S = 2^22
}

// ---------------- GEMM: C(MxN) = A(MxK, bf16) * Bt(NxK, bf16)^T ----------------
// MODE 0: f32 out; MODE 1: bf16 out; MODE 2: bf16 out, +bias, relu
// MODE 3: bf16 out, cols < Dd scaled by 0.125 (QKV projection: fold 1/sqrt(dk) into Q)
template <int MODE>
__global__ __launch_bounds__(256, 2) void gemm_bt(const u16* __restrict__ A,
                                                  const u16* __restrict__ Bt,
                                                  const float* __restrict__ bias,
                                                  void* __restrict__ C,
                                                  int M, int N, int K) {
  __shared__ alignas(16) u16 As[128 * 32];
  __shared__ alignas(16) u16 Bs[128 * 32];
  const int tid = threadIdx.x;
  const int lane = tid & 63;
  const int w = tid >> 6;
  const int wr = (w >> 1) * 64;
  const int wc = (w & 1) * 64;
  const int bm = blockIdx.y * 128;
  const int bn = blockIdx.x * 128;
  const int frow = lane & 15, fk = (lane >> 4) * 8;

  const int r0 = tid, r1 = 256 + tid;
  const u16* Ag0 = A + (size_t)(bm + (r0 >> 2)) * K + (r0 & 3) * 8;
  const u16* Ag1 = A + (size_t)(bm + (r1 >> 2)) * K + (r1 & 3) * 8;
  const u16* Bg0 = Bt + (size_t)(bn + (r0 >> 2)) * K + (r0 & 3) * 8;
  const u16* Bg1 = Bt + (size_t)(bn + (r1 >> 2)) * K + (r1 & 3) * 8;
  u16* As0 = As + (size_t)(w * 64) * 8;
  u16* As1 = As + (size_t)(256 + w * 64) * 8;
  u16* Bs0 = Bs + (size_t)(w * 64) * 8;
  u16* Bs1 = Bs + (size_t)(256 + w * 64) * 8;

  f32x4 acc[4][4] = {};

  for (int k0 = 0; k0 < K; k0 += 32) {
    gload_lds16(Ag0 + k0, As0);
    gload_lds16(Ag1 + k0, As1);
    gload_lds16(Bg0 + k0, Bs0);
    gload_lds16(Bg1 + k0, Bs1);
    __syncthreads();
    bf16x8 af[4], bfr[4];
#pragma unroll
    for (int m = 0; m < 4; m++) af[m] = *(const bf16x8*)&As[(wr + m * 16 + frow) * 32 + fk];
#pragma unroll
    for (int n = 0; n < 4; n++) bfr[n] = *(const bf16x8*)&Bs[(wc + n * 16 + frow) * 32 + fk];
#pragma unroll
    for (int m = 0; m < 4; m++)
#pragma unroll
      for (int n = 0; n < 4; n++)
        acc[m][n] = mfma16(af[m], bfr[n], acc[m][n]);
    __syncthreads();
  }

#pragma unroll
  for (int m = 0; m < 4; m++) {
#pragma unroll
    for (int n = 0; n < 4; n++) {
      const int col = bn + wc + n * 16 + frow;
      const float bv = (MODE == 2) ? bias[col] : 0.f;
      const float sc = (MODE == 3 && col < Dd) ? 0.125f : 1.f;
#pragma unroll
      for (int r = 0; r < 4; r++) {
        const int row = bm + wr + m * 16 + (lane >> 4) * 4 + r;  // verified C/D layout
        float v = acc[m][n][r];
        if (MODE == 2) v = fmaxf(v + bv, 0.f);
        if (MODE == 3) v *= sc;
        if (MODE == 0) ((float*)C)[(size_t)row * N + col] = v;
        else           ((u16*)C)[(size_t)row * N + col] = f2bf(v);
      }
    }
  }
}

// ---------------- fused flash attention (swapped QK^T + tr-read V + 2-phase dbuf) ----
// qkv: (B*S) x 3072 bf16 rows = [Q*0.125 | K | V]; out: (B*S) x 1024 bf16
// Per block: 64 q-rows (4 waves x 16), K-tiles of 64.
// K LDS: [buf][half d][kcol][32], d-chunk XOR-swizzled (slot = hi ^ (kcol&3)).
// V LDS: [buf] subtiled [n][ks][r][hi] of 4x16 (k x dk) tiles for ds_read_b64_tr_b16:
//   tr-read lane mapping (m156/m162): col=(addr>>3)&15, window=addr>>7, elem j -> +16j.
__global__ __launch_bounds__(256, 3) void attn_fwd(const u16* __restrict__ qkv,
                                                   const int* __restrict__ mask,
                                                   const int* __restrict__ mflag,
                                                   u16* __restrict__ outb) {
  __shared__ alignas(128) u16 Ks[2 * 4096];
  __shared__ alignas(128) u16 Vs[2 * 4096];
  __shared__ alignas(16)  u16 Pl[4 * 16 * 72];

  const int bx = blockIdx.x;
  const int qt = bx & 31;
  const int h = (bx >> 5) & 15;
  const int b = bx >> 9;
  const int tid = threadIdx.x;
  const int lane = tid & 63;
  const int w = tid >> 6;
  const int frow = lane & 15, hi = lane >> 4;
  const int qbase = qt * 64 + w * 16;

  bf16x8 qf[2];
  {
    const u16* qp = qkv + (size_t)(b * Ss + qbase + frow) * 3072 + h * 64 + hi * 8;
    qf[0] = *(const bf16x8*)(qp);
    qf[1] = *(const bf16x8*)(qp + 32);
  }
  const int allones = mflag[b];
  u16* Plw = Pl + w * (16 * 72);

  f32x4 oacc[4] = {};
  float mrow = -1e30f, lrow = 0.f;

  const size_t kvb = (size_t)(b * Ss) * 3072 + 1024 + h * 64;
  // K staging source: chunk tid -> (kcol, slot); global d-chunk = slot ^ (kcol&3)
  const int kcol_s = tid >> 2;
  const int dsw = ((tid & 3) ^ (kcol_s & 3)) * 8;
  const u16* Kg0 = qkv + kvb + (size_t)kcol_s * 3072 + dsw;
  const u16* Kg1 = Kg0 + 32;
  // V staging source: chunk p -> subtiled (k, dk)
  int kV0, dkV0, kV1, dkV1;
  {
    int p = tid, T = p >> 3, j = (p >> 1) & 3, hh = p & 1;
    kV0 = ((T >> 3) & 1) * 32 + (T & 3) * 8 + ((T >> 2) & 1) * 4 + j;
    dkV0 = ((T >> 4) & 3) * 16 + hh * 8;
    p = tid + 256; T = p >> 3; j = (p >> 1) & 3; hh = p & 1;
    kV1 = ((T >> 3) & 1) * 32 + (T & 3) * 8 + ((T >> 2) & 1) * 4 + j;
    dkV1 = ((T >> 4) & 3) * 16 + hh * 8;
  }
  const u16* Vg0 = qkv + kvb + 1024 + (size_t)kV0 * 3072 + dkV0;
  const u16* Vg1 = qkv + kvb + 1024 + (size_t)kV1 * 3072 + dkV1;

  const unsigned vbase = lds_addr(Vs) + lane * 8;

  // prologue: stage tile 0 into buf 0
  gload_lds16(Kg0, Ks + w * 512);
  gload_lds16(Kg1, Ks + 2048 + w * 512);
  gload_lds16(Vg0, Vs + w * 512);
  gload_lds16(Vg1, Vs + 2048 + w * 512);
  __syncthreads();

#pragma unroll 1
  for (int kt = 0; kt < 32; kt++) {
    const int cur = kt & 1;
    // prefetch next tile into other buffer (lands during this tile's compute)
    if (kt < 31) {
      const size_t soff = (size_t)(kt + 1) * 64 * 3072;
      u16* Kb = Ks + (cur ^ 1) * 4096;
      u16* Vb = Vs + (cur ^ 1) * 4096;
      gload_lds16(Kg0 + soff, Kb + w * 512);
      gload_lds16(Kg1 + soff, Kb + 2048 + w * 512);
      gload_lds16(Vg0 + soff, Vb + w * 512);
      gload_lds16(Vg1 + soff, Vb + 2048 + w * 512);
    }
    const u16* Kbuf = Ks + cur * 4096;

    // S^T = K Q^T : lane holds S[k = n*16+hi*4+r][q = qbase+frow]
    f32x4 sacc[4] = {};
    const int kswz = (hi ^ (frow & 3)) * 8;
#pragma unroll
    for (int ks = 0; ks < 2; ks++)
#pragma unroll
      for (int n = 0; n < 4; n++) {
        bf16x8 kf = *(const bf16x8*)&Kbuf[ks * 2048 + (n * 16 + frow) * 32 + kswz];
        sacc[n] = mfma16(kf, qf[ks], sacc[n]);
      }

    const int srow = kt * 64;
    float sv[16];
#pragma unroll
    for (int n = 0; n < 4; n++)
#pragma unroll
      for (int r = 0; r < 4; r++) {
        float s = sacc[n][r];  // scale already folded into Q
        if (!allones) {
          const int qq = b * Ss + qbase + frow;
          const int kk = srow + n * 16 + hi * 4 + r;
          if (mask[(size_t)qq * Ss + kk] == 0) s = -1e30f;
        }
        sv[n * 4 + r] = s;
      }
    // row max for q=frow: in-lane tree + reduce across the 4 hi-lanes
    float mt = sv[0];
#pragma unroll
    for (int i = 1; i < 16; i++) mt = fmaxf(mt, sv[i]);
    mt = fmaxf(mt, __shfl_xor(mt, 16));
    mt = fmaxf(mt, __shfl_xor(mt, 32));
    const float mn = fmaxf(mrow, mt);
    const float al = __expf(mrow - mn);
    mrow = mn;
    float ps[16], rs = 0.f;
#pragma unroll
    for (int i = 0; i < 16; i++) { ps[i] = __expf(sv[i] - mn); rs += ps[i]; }
    rs += __shfl_xor(rs, 16);
    rs += __shfl_xor(rs, 32);
    lrow = lrow * al + rs;
    // rescale O: need alpha of q-row hi*4+r (held by lane frow=hi*4+r)
    float alr[4];
#pragma unroll
    for (int r = 0; r < 4; r++) alr[r] = __shfl(al, (lane & 48) | (hi * 4 + r));
#pragma unroll
    for (int n = 0; n < 4; n++) {
      oacc[n][0] *= alr[0]; oacc[n][1] *= alr[1];
      oacc[n][2] *= alr[2]; oacc[n][3] *= alr[3];
    }
    // write P[q][k] (2-way banked: stride 72)
#pragma unroll
    for (int n = 0; n < 4; n++)
#pragma unroll
      for (int r = 0; r < 4; r++)
        Plw[frow * 72 + n * 16 + hi * 4 + r] = f2bf(ps[n * 4 + r]);

    // O += P V via hardware-transpose V reads
    const unsigned vaddr = vbase + (cur << 13);
    u16x4 t0, t1, t2, t3, t4, t5, t6, t7;
    // ks = 0 (offsets = (n*4 + ks*2 + r) * 512)
    TRRD(t0, vaddr, 0);    TRRD(t1, vaddr, 512);
    TRRD(t2, vaddr, 2048); TRRD(t3, vaddr, 2560);
    TRRD(t4, vaddr, 4096); TRRD(t5, vaddr, 4608);
    TRRD(t6, vaddr, 6144); TRRD(t7, vaddr, 6656);
    {
      bf16x8 pa = *(const bf16x8*)&Plw[frow * 72 + hi * 8];
      asm volatile("s_waitcnt lgkmcnt(0)" ::: "memory");
      __builtin_amdgcn_sched_barrier(0);
      oacc[0] = mfma16(pa, cat8(t0, t1), oacc[0]);
      oacc[1] = mfma16(pa, cat8(t2, t3), oacc[1]);
      oacc[2] = mfma16(pa, cat8(t4, t5), oacc[2]);
      oacc[3] = mfma16(pa, cat8(t6, t7), oacc[3]);
    }
    // ks = 1
    TRRD(t0, vaddr, 1024); TRRD(t1, vaddr, 1536);
    TRRD(t2, vaddr, 3072); TRRD(t3, vaddr, 3584);
    TRRD(t4, vaddr, 5120); TRRD(t5, vaddr, 5632);
    TRRD(t6, vaddr, 7168); TRRD(t7, vaddr, 7680);
    {
      bf16x8 pa = *(const bf16x8*)&Plw[frow * 72 + 32 + hi * 8];
      asm volatile("s_waitcnt lgkmcnt(0)" ::: "memory");
      __builtin_amdgcn_sched_barrier(0);
      oacc[0] = mfma16(pa, cat8(t0, t1), oacc[0]);
      oacc[1] = mfma16(pa, cat8(t2, t3), oacc[1]);
      oacc[2] = mfma16(pa, cat8(t4, t5), oacc[2]);
      oacc[3] = mfma16(pa, cat8(t6, t7), oacc[3]);
    }
    __syncthreads();
  }

  // epilogue: divide by l (held at lane frow = hi*4+r) and store
  float lr[4];
#pragma unroll
  for (int r = 0; r < 4; r++) lr[r] = __shfl(lrow, (lane & 48) | (hi * 4 + r));
#pragma unroll
  for (int n = 0; n < 4; n++)
#pragma unroll
    for (int r = 0; r < 4; r++) {
      const int q = qbase + hi * 4 + r;
      const int dk = n * 16 + frow;
      outb[(size_t)(b * Ss + q) * 1024 + h * 64 + dk] = f2bf(oacc[n][r] / lr[r]);
    }
}

// ---------------- fused residual + bias + LayerNorm ----------------
__global__ __launch_bounds__(256) void ln_fuse(const float* __restrict__ a,
                                               const float* __restrict__ c,
                                               const float* __restrict__ bias,
                                               const float* __restrict__ g,
                                               const float* __restrict__ be,
                                               float* __restrict__ of,
                                               u16* __restrict__ ob) {
  __shared__ float red[4];
  const int tid = threadIdx.x;
  const size_t base = (size_t)blockIdx.x * 1024 + tid * 4;
  float4 va = *(const float4*)(a + base);
  float4 vc = *(const float4*)(c + base);
  float4 vb = *(const float4*)(bias + tid * 4);
  const float s0 = va.x + vc.x + vb.x, s1 = va.y + vc.y + vb.y;
  const float s2 = va.z + vc.z + vb.z, s3 = va.w + vc.w + vb.w;
  float sum = s0 + s1 + s2 + s3;
#pragma unroll
  for (int o = 32; o; o >>= 1) sum += __shfl_xor(sum, o);
  if ((tid & 63) == 0) red[tid >> 6] = sum;
  __syncthreads();
  const float mu = (red[0] + red[1] + red[2] + red[3]) * (1.f / 1024.f);
  __syncthreads();
  const float d0 = s0 - mu, d1 = s1 - mu, d2 = s2 - mu, d3 = s3 - mu;
  float vs = d0 * d0 + d1 * d1 + d2 * d2 + d3 * d3;
#pragma unroll
  for (int o = 32; o; o >>= 1) vs += __shfl_xor(vs, o);
  if ((tid & 63) == 0) red[tid >> 6] = vs;
  __syncthreads();
  const float var = (red[0] + red[1] + red[2] + red[3]) * (1.f / 1024.f);
  const float rs = rsqrtf(var + 1e-5f);
  float4 vg = *(const float4*)(g + tid * 4);
  float4 ve = *(const float4*)(be + tid * 4);
  const float y0 = d0 * rs * vg.x + ve.x, y1 = d1 * rs * vg.y + ve.y;
  const float y2 = d2 * rs * vg.z + ve.z, y3 = d3 * rs * vg.w + ve.w;
  if (of) { float4 y; y.x = y0; y.y = y1; y.z = y2; y.w = y3; *(float4*)(of + base) = y; }
  if (ob) { u16x4 o; o[0] = f2bf(y0); o[1] = f2bf(y1); o[2] = f2bf(y2); o[3] = f2bf(y3);
            *(u16x4*)(ob + base) = o; }
}

extern "C" void kernel_launch(void* const* d_in, const int* in_sizes, int n_in,
                              void* d_out, int out_size, void* d_ws, size_t ws_size,
                              hipStream_t stream) {
  const float* src = (const float*)d_in[0];
  const int* mask = (const int*)d_in[1];
  const float* Wq = (const float*)d_in[2];
  const float* Wk = (const float*)d_in[3];
  const float* Wv = (const float*)d_in[4];
  const float* Wo = (const float*)d_in[5];
  const float* bo = (const float*)d_in[6];
  const float* g1 = (const float*)d_in[7];
  const float* be1 = (const float*)d_in[8];
  const float* W1 = (const float*)d_in[9];
  const float* b1 = (const float*)d_in[10];
  const float* W2 = (const float*)d_in[11];
  const float* b2 = (const float*)d_in[12];
  const float* g2 = (const float*)d_in[13];
  const float* be2 = (const float*)d_in[14];
  float* outp = (float*)d_out;
  (void)in_sizes; (void)n_in; (void)out_size; (void)ws_size;

  char* ws = (char*)d_ws;
  size_t off = 0;
  auto take = [&](size_t bytes) -> char* {
    char* p = ws + off;
    off = (off + bytes + 255) & ~(size_t)255;
    return p;
  };
  u16* srcb  = (u16*)take((size_t)BS * Dd * 2);
  u16* wqkvt = (u16*)take((size_t)3 * Dd * Dd * 2);
  u16* wot   = (u16*)take((size_t)Dd * Dd * 2);
  u16* w1t   = (u16*)take((size_t)Dd * DFF * 2);
  u16* w2t   = (u16*)take((size_t)DFF * Dd * 2);
  char* qkvr = take((size_t)BS * 3 * Dd * 2);  // qkv bf16; later reused as C1/C2 f32
  u16* qkvb  = (u16*)qkvr;
  float* Cf  = (float*)qkvr;
  u16* attnb = (u16*)take((size_t)BS * Dd * 2);  // attn out bf16; later x bf16
  float* xf  = (float*)take((size_t)BS * Dd * 4);
  u16* hb    = (u16*)take((size_t)BS * DFF * 2);
  int* flags = (int*)take(256);

  cast_src_k<<<2048, 256, 0, stream>>>(src, srcb, BS * Dd);
  transpose_cast<<<dim3(32, 32), 256, 0, stream>>>(Wq, wqkvt,                Dd, Dd);
  transpose_cast<<<dim3(32, 32), 256, 0, stream>>>(Wk, wqkvt + Dd * Dd,      Dd, Dd);
  transpose_cast<<<dim3(32, 32), 256, 0, stream>>>(Wv, wqkvt + 2 * Dd * Dd,  Dd, Dd);
  transpose_cast<<<dim3(32, 32), 256, 0, stream>>>(Wo, wot, Dd, Dd);
  transpose_cast<<<dim3(128, 32), 256, 0, stream>>>(W1, w1t, Dd, DFF);
  transpose_cast<<<dim3(32, 128), 256, 0, stream>>>(W2, w2t, DFF, Dd);
  mask_init_k<<<1, 64, 0, stream>>>(flags);
  mask_check_k<<<2048, 256, 0, stream>>>(mask, flags, Bb * Ss * Ss);

  // QKV projection (Q pre-scaled by 0.125 in epilogue)
  gemm_bt<3><<<dim3(3 * Dd / 128, BS / 128), 256, 0, stream>>>(srcb, wqkvt, nullptr, qkvb,
                                                               BS, 3 * Dd, Dd);
  attn_fwd<<<Bb * Hh * (Ss / 64), 256, 0, stream>>>(qkvb, mask, flags, attnb);
  gemm_bt<0><<<dim3(Dd / 128, BS / 128), 256, 0, stream>>>(attnb, wot, nullptr, Cf,
                                                           BS, Dd, Dd);
  ln_fuse<<<BS, 256, 0, stream>>>(src, Cf, bo, g1, be1, xf, attnb);
  gemm_bt<2><<<dim3(DFF / 128, BS / 128), 256, 0, stream>>>(attnb, w1t, b1, hb,
                                                            BS, DFF, Dd);
  gemm_bt<0><<<dim3(Dd / 128, BS / 128), 256, 0, stream>>>(hb, w2t, nullptr, Cf,
                                                           BS, Dd, DFF);
  ln_fuse<<<BS, 256, 0, stream>>>(xf, Cf, b2, g2, be2, outp, nullptr);
}

// Round 3
// 667.310 us; speedup vs baseline: 1.2527x; 1.0379x over previous
//
#include <hip/hip_runtime.h>

#define DEV static __device__ __forceinline__

typedef unsigned short u16;
typedef __attribute__((ext_vector_type(8))) short bf16x8;     // 8 bf16 in 4 VGPRs
typedef __attribute__((ext_vector_type(8))) unsigned short u16x8;
typedef __attribute__((ext_vector_type(4))) unsigned short u16x4;
typedef __attribute__((ext_vector_type(4))) float f32x4;

static constexpr int Bb = 4, Ss = 2048, Dd = 1024, Hh = 16, DFF = 4096;
static constexpr int BS = Bb * Ss;  // 8192 rows

DEV u16 f2bf(float f) {
  union { float f; unsigned u; } x; x.f = f;
  unsigned r = x.u + 0x7fffu + ((x.u >> 16) & 1u);  // RNE
  return (u16)(r >> 16);
}

DEV void gload_lds16(const void* g, void* l) {
  __builtin_amdgcn_global_load_lds(
      (const __attribute__((address_space(1))) unsigned int*)g,
      (__attribute__((address_space(3))) unsigned int*)l, 16, 0, 0);
}

DEV unsigned lds_addr(const void* p) {
  return (unsigned)(size_t)(const __attribute__((address_space(3))) void*)p;
}

DEV f32x4 mfma16(bf16x8 a, bf16x8 b, f32x4 c) {
  return __builtin_amdgcn_mfma_f32_16x16x32_bf16(a, b, c, 0, 0, 0);
}

DEV bf16x8 cat8(u16x4 a, u16x4 b) {
  bf16x8 v;
#pragma unroll
  for (int j = 0; j < 4; j++) { v[j] = (short)a[j]; v[j + 4] = (short)b[j]; }
  return v;
}

#define TRRD(dst, addr, OFF)                                     \
  asm volatile("ds_read_b64_tr_b16 %0, %1 offset:" #OFF         \
               : "=v"(dst) : "v"(addr))

// ---------------- elementwise cast fp32 -> bf16 ----------------
__global__ void cast_src_k(const float* __restrict__ in, u16* __restrict__ outp, int n) {
  int i = (blockIdx.x * 256 + threadIdx.x) * 4;
  const int stride = gridDim.x * 256 * 4;
  for (; i < n; i += stride) {
    float4 v = *(const float4*)(in + i);
    u16x4 o; o[0] = f2bf(v.x); o[1] = f2bf(v.y); o[2] = f2bf(v.z); o[3] = f2bf(v.w);
    *(u16x4*)(outp + i) = o;
  }
}

// ---------------- transpose + cast: W (KxN f32) -> Wt (NxK bf16) ----------------
__global__ __launch_bounds__(256) void transpose_cast(const float* __restrict__ W,
                                                      u16* __restrict__ Wt, int K, int N) {
  __shared__ float t[32][33];
  const int n0 = blockIdx.x * 32, k0 = blockIdx.y * 32;
  const int tx = threadIdx.x & 31, ty = threadIdx.x >> 5;
#pragma unroll
  for (int i = 0; i < 4; i++) t[ty + i * 8][tx] = W[(size_t)(k0 + ty + i * 8) * N + n0 + tx];
  __syncthreads();
#pragma unroll
  for (int i = 0; i < 4; i++) Wt[(size_t)(n0 + ty + i * 8) * K + k0 + tx] = f2bf(t[tx][ty + i * 8]);
}

// ---------------- mask summary ----------------
__global__ void mask_init_k(int* flags) { if (threadIdx.x < 4) flags[threadIdx.x] = 1; }
__global__ void mask_check_k(const int* __restrict__ mask, int* __restrict__ flags, int n) {
  int i = blockIdx.x * 256 + threadIdx.x;
  const int st = gridDim.x * 256;
  for (; i < n; i += st) if (mask[i] == 0) flags[i >> 22] = 0;  // S*S = 2^22
}

// ---------------- 128^2 GEMM (m97 structure): C = A * Bt^T ----------------
// MODE 0: f32 out; MODE 1: bf16 out; MODE 2: bf16 +bias relu; MODE 3: bf16, col<Dd *0.125
template <int MODE>
__global__ __launch_bounds__(256, 2) void gemm_bt(const u16* __restrict__ A,
                                                  const u16* __restrict__ Bt,
                                                  const float* __restrict__ bias,
                                                  void* __restrict__ C,
                                                  int M, int N, int K) {
  __shared__ alignas(16) u16 As[128 * 32];
  __shared__ alignas(16) u16 Bs[128 * 32];
  const int tid = threadIdx.x;
  const int lane = tid & 63;
  const int w = tid >> 6;
  const int wr = (w >> 1) * 64;
  const int wc = (w & 1) * 64;
  const int bm = blockIdx.y * 128;
  const int bn = blockIdx.x * 128;
  const int frow = lane & 15, fk = (lane >> 4) * 8;

  const int r0 = tid, r1 = 256 + tid;
  const u16* Ag0 = A + (size_t)(bm + (r0 >> 2)) * K + (r0 & 3) * 8;
  const u16* Ag1 = A + (size_t)(bm + (r1 >> 2)) * K + (r1 & 3) * 8;
  const u16* Bg0 = Bt + (size_t)(bn + (r0 >> 2)) * K + (r0 & 3) * 8;
  const u16* Bg1 = Bt + (size_t)(bn + (r1 >> 2)) * K + (r1 & 3) * 8;
  u16* As0 = As + (size_t)(w * 64) * 8;
  u16* As1 = As + (size_t)(256 + w * 64) * 8;
  u16* Bs0 = Bs + (size_t)(w * 64) * 8;
  u16* Bs1 = Bs + (size_t)(256 + w * 64) * 8;

  f32x4 acc[4][4] = {};

  for (int k0 = 0; k0 < K; k0 += 32) {
    gload_lds16(Ag0 + k0, As0);
    gload_lds16(Ag1 + k0, As1);
    gload_lds16(Bg0 + k0, Bs0);
    gload_lds16(Bg1 + k0, Bs1);
    __syncthreads();
    bf16x8 af[4], bfr[4];
#pragma unroll
    for (int m = 0; m < 4; m++) af[m] = *(const bf16x8*)&As[(wr + m * 16 + frow) * 32 + fk];
#pragma unroll
    for (int n = 0; n < 4; n++) bfr[n] = *(const bf16x8*)&Bs[(wc + n * 16 + frow) * 32 + fk];
#pragma unroll
    for (int m = 0; m < 4; m++)
#pragma unroll
      for (int n = 0; n < 4; n++)
        acc[m][n] = mfma16(af[m], bfr[n], acc[m][n]);
    __syncthreads();
  }

#pragma unroll
  for (int m = 0; m < 4; m++) {
#pragma unroll
    for (int n = 0; n < 4; n++) {
      const int col = bn + wc + n * 16 + frow;
      const float bv = (MODE == 2) ? bias[col] : 0.f;
      const float sc = (MODE == 3 && col < Dd) ? 0.125f : 1.f;
#pragma unroll
      for (int r = 0; r < 4; r++) {
        const int row = bm + wr + m * 16 + (lane >> 4) * 4 + r;
        float v = acc[m][n][r];
        if (MODE == 2) v = fmaxf(v + bv, 0.f);
        if (MODE == 3) v *= sc;
        if (MODE == 0) ((float*)C)[(size_t)row * N + col] = v;
        else           ((u16*)C)[(size_t)row * N + col] = f2bf(v);
      }
    }
  }
}

// ---------------- 256^2 8-phase GEMM (T2+T3+T4+T5) ----------------
// 512 thr = 8 waves (2M x 4N), BM=BN=256, BK=64, per-wave C = 128x64.
// LDS 128 KiB: A[slot][half 128r][64k], B likewise at +32768 (u16 units).
// Reads XOR-swizzled elem ^= (row&7)<<3; staging source pre-swizzled (both-sides).
// Phase ring: stage {B(T+1)h0,h1, A(T+2)h0,h1, B(T+2)h0,h1, A(T+3)h0,h1} at ph1..8;
// vmcnt(4) checkpoints at ph4/ph8 guarantee landing 1 phase before first read;
// write-after-read: each region staged >=1 barrier after its last read.
template <int MODE>
__global__ __launch_bounds__(512, 2) void gemm8p(const u16* __restrict__ A,
                                                 const u16* __restrict__ Bt,
                                                 const float* __restrict__ bias,
                                                 void* __restrict__ C,
                                                 int M, int N, int K) {
  __shared__ alignas(128) u16 lds[65536];
  const int tid = threadIdx.x, lane = tid & 63, w = tid >> 6;
  const int wm = w >> 2, wc = w & 3;
  const int frow = lane & 15, hi = lane >> 4;
  const int bm = blockIdx.y * 256, bn = blockIdx.x * 256;
  const int NT = K >> 6;

  // staging: thread covers rows sr, sr+64 (within half), col chunk cs (pre-swizzled)
  const int cs = ((tid & 7) ^ ((tid >> 3) & 7)) * 8;
  const int sr = w * 8 + ((lane >> 3) & 7);
  const u16* Ab = A + (size_t)(bm + sr) * K + cs;
  const u16* Bbp = Bt + (size_t)(bn + sr) * K + cs;
  u16* lw = lds + w * 512;

  // fragment read bases (u16 offsets), swizzled col
  const int c0 = (hi * 8) ^ ((frow & 7) << 3);
  const u16* Abase = lds + wm * 8192 + frow * 64;
  const u16* Bbase = lds + 32768 + (wc >> 1) * 8192 + (wc & 1) * 4096 + frow * 64;

  f32x4 acc[8][4] = {};
  bf16x8 af0[4][2], af1[4][2], bf0[2][2], bf1[2][2];

#define STG(Pb, hh, kk, reg)                                                     \
  do {                                                                           \
    gload_lds16((Pb) + (size_t)((hh) * 128) * K + (kk), lw + (reg));             \
    gload_lds16((Pb) + (size_t)((hh) * 128 + 64) * K + (kk), lw + (reg) + 4096); \
  } while (0)
#define LDA(dst, sb, mh)                                                              \
  do {                                                                                \
    _Pragma("unroll") for (int m = 0; m < 4; m++) {                                   \
      dst[m][0] = *(const bf16x8*)(Abase + (sb) + ((mh) * 4 + m) * 1024 + c0);        \
      dst[m][1] = *(const bf16x8*)(Abase + (sb) + ((mh) * 4 + m) * 1024 + (c0 ^ 32)); \
    }                                                                                 \
  } while (0)
#define LDB(dst, sb, nh)                                                              \
  do {                                                                                \
    _Pragma("unroll") for (int n = 0; n < 2; n++) {                                   \
      dst[n][0] = *(const bf16x8*)(Bbase + (sb) + ((nh) * 2 + n) * 1024 + c0);        \
      dst[n][1] = *(const bf16x8*)(Bbase + (sb) + ((nh) * 2 + n) * 1024 + (c0 ^ 32)); \
    }                                                                                 \
  } while (0)
#define MM(AF, BF, mh, nh)                                                             \
  do {                                                                                 \
    __builtin_amdgcn_s_setprio(1);                                                     \
    _Pragma("unroll") for (int m = 0; m < 4; m++) _Pragma("unroll") for (int n = 0;    \
                                                                        n < 2; n++) { \
      acc[(mh)*4+m][(nh)*2+n] = mfma16(AF[m][0], BF[n][0], acc[(mh)*4+m][(nh)*2+n]);   \
      acc[(mh)*4+m][(nh)*2+n] = mfma16(AF[m][1], BF[n][1], acc[(mh)*4+m][(nh)*2+n]);   \
    }                                                                                  \
    __builtin_amdgcn_s_setprio(0);                                                     \
  } while (0)
#define BAR asm volatile("s_barrier" ::: "memory")
#define VMC(n) asm volatile("s_waitcnt vmcnt(" #n ")" ::: "memory")

  // prologue: A(0)->A0, B(0)->B0, A(1)->A1
  STG(Ab, 0, 0, 0);        STG(Ab, 1, 0, 8192);
  STG(Bbp, 0, 0, 32768);   STG(Bbp, 1, 0, 40960);
  STG(Ab, 0, 64, 16384);   STG(Ab, 1, 64, 24576);
  VMC(0);
  BAR;

  const int NI = NT >> 1;
#pragma unroll 1
  for (int i = 0; i < NI; ++i) {
    const int T = i * 2;
    const int kT1 = (T + 1) << 6;
    const int kT2 = (T + 2 < NT ? T + 2 : NT - 1) << 6;
    const int kT3 = (T + 3 < NT ? T + 3 : NT - 1) << 6;
    // ph1: read A0 m0-3 + B0 n0-1; stage B1-h0 (T+1); MFMA Q(0,0) slot0
    LDA(af0, 0, 0); LDB(bf0, 0, 0);
    STG(Bbp, 0, kT1, 49152);
    BAR; MM(af0, bf0, 0, 0); BAR;
    // ph2: read A0 m4-7; stage B1-h1; MFMA Q(1,0)
    LDA(af1, 0, 1);
    STG(Bbp, 1, kT1, 57344);
    BAR; MM(af1, bf0, 1, 0); BAR;
    // ph3: read B0 n2-3; stage A0-h0 (T+2); MFMA Q(0,1)
    LDB(bf1, 0, 1);
    STG(Ab, 0, kT2, 0);
    BAR; MM(af0, bf1, 0, 1); BAR;
    // ph4: stage A0-h1 (T+2); vmcnt(4); MFMA Q(1,1)
    STG(Ab, 1, kT2, 8192);
    VMC(4); BAR; MM(af1, bf1, 1, 1); BAR;
    // ph5: read A1 m0-3 + B1 n0-1; stage B0-h0 (T+2); MFMA slot1 Q(0,0)
    LDA(af0, 16384, 0); LDB(bf0, 16384, 0);
    STG(Bbp, 0, kT2, 32768);
    BAR; MM(af0, bf0, 0, 0); BAR;
    // ph6: read A1 m4-7; stage B0-h1 (T+2); MFMA Q(1,0)
    LDA(af1, 16384, 1);
    STG(Bbp, 1, kT2, 40960);
    BAR; MM(af1, bf0, 1, 0); BAR;
    // ph7: read B1 n2-3; stage A1-h0 (T+3); MFMA Q(0,1)
    LDB(bf1, 16384, 1);
    STG(Ab, 0, kT3, 16384);
    BAR; MM(af0, bf1, 0, 1); BAR;
    // ph8: stage A1-h1 (T+3); vmcnt(4); MFMA Q(1,1)
    STG(Ab, 1, kT3, 24576);
    VMC(4); BAR; MM(af1, bf1, 1, 1); BAR;
  }

#undef STG
#undef LDA
#undef LDB
#undef MM
#undef BAR
#undef VMC

#pragma unroll
  for (int m = 0; m < 8; m++) {
#pragma unroll
    for (int n = 0; n < 4; n++) {
      const int col = bn + wc * 64 + n * 16 + frow;
      const float bv = (MODE == 2) ? bias[col] : 0.f;
      const float sc = (MODE == 3 && col < Dd) ? 0.125f : 1.f;
#pragma unroll
      for (int r = 0; r < 4; r++) {
        const int row = bm + wm * 128 + m * 16 + hi * 4 + r;
        float v = acc[m][n][r];
        if (MODE == 2) v = fmaxf(v + bv, 0.f);
        if (MODE == 3) v *= sc;
        if (MODE == 0) ((float*)C)[(size_t)row * N + col] = v;
        else           ((u16*)C)[(size_t)row * N + col] = f2bf(v);
      }
    }
  }
}

// ---------------- fused flash attention (unchanged from R2) ----------------
__global__ __launch_bounds__(256, 3) void attn_fwd(const u16* __restrict__ qkv,
                                                   const int* __restrict__ mask,
                                                   const int* __restrict__ mflag,
                                                   u16* __restrict__ outb) {
  __shared__ alignas(128) u16 Ks[2 * 4096];
  __shared__ alignas(128) u16 Vs[2 * 4096];
  __shared__ alignas(16)  u16 Pl[4 * 16 * 72];

  const int bx = blockIdx.x;
  const int qt = bx & 31;
  const int h = (bx >> 5) & 15;
  const int b = bx >> 9;
  const int tid = threadIdx.x;
  const int lane = tid & 63;
  const int w = tid >> 6;
  const int frow = lane & 15, hi = lane >> 4;
  const int qbase = qt * 64 + w * 16;

  bf16x8 qf[2];
  {
    const u16* qp = qkv + (size_t)(b * Ss + qbase + frow) * 3072 + h * 64 + hi * 8;
    qf[0] = *(const bf16x8*)(qp);
    qf[1] = *(const bf16x8*)(qp + 32);
  }
  const int allones = mflag[b];
  u16* Plw = Pl + w * (16 * 72);

  f32x4 oacc[4] = {};
  float mrow = -1e30f, lrow = 0.f;

  const size_t kvb = (size_t)(b * Ss) * 3072 + 1024 + h * 64;
  const int kcol_s = tid >> 2;
  const int dsw = ((tid & 3) ^ (kcol_s & 3)) * 8;
  const u16* Kg0 = qkv + kvb + (size_t)kcol_s * 3072 + dsw;
  const u16* Kg1 = Kg0 + 32;
  int kV0, dkV0, kV1, dkV1;
  {
    int p = tid, T = p >> 3, j = (p >> 1) & 3, hh = p & 1;
    kV0 = ((T >> 3) & 1) * 32 + (T & 3) * 8 + ((T >> 2) & 1) * 4 + j;
    dkV0 = ((T >> 4) & 3) * 16 + hh * 8;
    p = tid + 256; T = p >> 3; j = (p >> 1) & 3; hh = p & 1;
    kV1 = ((T >> 3) & 1) * 32 + (T & 3) * 8 + ((T >> 2) & 1) * 4 + j;
    dkV1 = ((T >> 4) & 3) * 16 + hh * 8;
  }
  const u16* Vg0 = qkv + kvb + 1024 + (size_t)kV0 * 3072 + dkV0;
  const u16* Vg1 = qkv + kvb + 1024 + (size_t)kV1 * 3072 + dkV1;

  const unsigned vbase = lds_addr(Vs) + lane * 8;

  gload_lds16(Kg0, Ks + w * 512);
  gload_lds16(Kg1, Ks + 2048 + w * 512);
  gload_lds16(Vg0, Vs + w * 512);
  gload_lds16(Vg1, Vs + 2048 + w * 512);
  __syncthreads();

#pragma unroll 1
  for (int kt = 0; kt < 32; kt++) {
    const int cur = kt & 1;
    if (kt < 31) {
      const size_t soff = (size_t)(kt + 1) * 64 * 3072;
      u16* Kb = Ks + (cur ^ 1) * 4096;
      u16* Vb = Vs + (cur ^ 1) * 4096;
      gload_lds16(Kg0 + soff, Kb + w * 512);
      gload_lds16(Kg1 + soff, Kb + 2048 + w * 512);
      gload_lds16(Vg0 + soff, Vb + w * 512);
      gload_lds16(Vg1 + soff, Vb + 2048 + w * 512);
    }
    const u16* Kbuf = Ks + cur * 4096;

    f32x4 sacc[4] = {};
    const int kswz = (hi ^ (frow & 3)) * 8;
#pragma unroll
    for (int ks = 0; ks < 2; ks++)
#pragma unroll
      for (int n = 0; n < 4; n++) {
        bf16x8 kf = *(const bf16x8*)&Kbuf[ks * 2048 + (n * 16 + frow) * 32 + kswz];
        sacc[n] = mfma16(kf, qf[ks], sacc[n]);
      }

    const int srow = kt * 64;
    float sv[16];
#pragma unroll
    for (int n = 0; n < 4; n++)
#pragma unroll
      for (int r = 0; r < 4; r++) {
        float s = sacc[n][r];
        if (!allones) {
          const int qq = b * Ss + qbase + frow;
          const int kk = srow + n * 16 + hi * 4 + r;
          if (mask[(size_t)qq * Ss + kk] == 0) s = -1e30f;
        }
        sv[n * 4 + r] = s;
      }
    float mt = sv[0];
#pragma unroll
    for (int i = 1; i < 16; i++) mt = fmaxf(mt, sv[i]);
    mt = fmaxf(mt, __shfl_xor(mt, 16));
    mt = fmaxf(mt, __shfl_xor(mt, 32));
    const float mn = fmaxf(mrow, mt);
    const float al = __expf(mrow - mn);
    mrow = mn;
    float ps[16], rs = 0.f;
#pragma unroll
    for (int i = 0; i < 16; i++) { ps[i] = __expf(sv[i] - mn); rs += ps[i]; }
    rs += __shfl_xor(rs, 16);
    rs += __shfl_xor(rs, 32);
    lrow = lrow * al + rs;
    float alr[4];
#pragma unroll
    for (int r = 0; r < 4; r++) alr[r] = __shfl(al, (lane & 48) | (hi * 4 + r));
#pragma unroll
    for (int n = 0; n < 4; n++) {
      oacc[n][0] *= alr[0]; oacc[n][1] *= alr[1];
      oacc[n][2] *= alr[2]; oacc[n][3] *= alr[3];
    }
#pragma unroll
    for (int n = 0; n < 4; n++)
#pragma unroll
      for (int r = 0; r < 4; r++)
        Plw[frow * 72 + n * 16 + hi * 4 + r] = f2bf(ps[n * 4 + r]);

    const unsigned vaddr = vbase + (cur << 13);
    u16x4 t0, t1, t2, t3, t4, t5, t6, t7;
    TRRD(t0, vaddr, 0);    TRRD(t1, vaddr, 512);
    TRRD(t2, vaddr, 2048); TRRD(t3, vaddr, 2560);
    TRRD(t4, vaddr, 4096); TRRD(t5, vaddr, 4608);
    TRRD(t6, vaddr, 6144); TRRD(t7, vaddr, 6656);
    {
      bf16x8 pa = *(const bf16x8*)&Plw[frow * 72 + hi * 8];
      asm volatile("s_waitcnt lgkmcnt(0)" ::: "memory");
      __builtin_amdgcn_sched_barrier(0);
      oacc[0] = mfma16(pa, cat8(t0, t1), oacc[0]);
      oacc[1] = mfma16(pa, cat8(t2, t3), oacc[1]);
      oacc[2] = mfma16(pa, cat8(t4, t5), oacc[2]);
      oacc[3] = mfma16(pa, cat8(t6, t7), oacc[3]);
    }
    TRRD(t0, vaddr, 1024); TRRD(t1, vaddr, 1536);
    TRRD(t2, vaddr, 3072); TRRD(t3, vaddr, 3584);
    TRRD(t4, vaddr, 5120); TRRD(t5, vaddr, 5632);
    TRRD(t6, vaddr, 7168); TRRD(t7, vaddr, 7680);
    {
      bf16x8 pa = *(const bf16x8*)&Plw[frow * 72 + 32 + hi * 8];
      asm volatile("s_waitcnt lgkmcnt(0)" ::: "memory");
      __builtin_amdgcn_sched_barrier(0);
      oacc[0] = mfma16(pa, cat8(t0, t1), oacc[0]);
      oacc[1] = mfma16(pa, cat8(t2, t3), oacc[1]);
      oacc[2] = mfma16(pa, cat8(t4, t5), oacc[2]);
      oacc[3] = mfma16(pa, cat8(t6, t7), oacc[3]);
    }
    __syncthreads();
  }

  float lr[4];
#pragma unroll
  for (int r = 0; r < 4; r++) lr[r] = __shfl(lrow, (lane & 48) | (hi * 4 + r));
#pragma unroll
  for (int n = 0; n < 4; n++)
#pragma unroll
    for (int r = 0; r < 4; r++) {
      const int q = qbase + hi * 4 + r;
      const int dk = n * 16 + frow;
      outb[(size_t)(b * Ss + q) * 1024 + h * 64 + dk] = f2bf(oacc[n][r] / lr[r]);
    }
}

// ---------------- fused residual + bias + LayerNorm ----------------
__global__ __launch_bounds__(256) void ln_fuse(const float* __restrict__ a,
                                               const float* __restrict__ c,
                                               const float* __restrict__ bias,
                                               const float* __restrict__ g,
                                               const float* __restrict__ be,
                                               float* __restrict__ of,
                                               u16* __restrict__ ob) {
  __shared__ float red[4];
  const int tid = threadIdx.x;
  const size_t base = (size_t)blockIdx.x * 1024 + tid * 4;
  float4 va = *(const float4*)(a + base);
  float4 vc = *(const float4*)(c + base);
  float4 vb = *(const float4*)(bias + tid * 4);
  const float s0 = va.x + vc.x + vb.x, s1 = va.y + vc.y + vb.y;
  const float s2 = va.z + vc.z + vb.z, s3 = va.w + vc.w + vb.w;
  float sum = s0 + s1 + s2 + s3;
#pragma unroll
  for (int o = 32; o; o >>= 1) sum += __shfl_xor(sum, o);
  if ((tid & 63) == 0) red[tid >> 6] = sum;
  __syncthreads();
  const float mu = (red[0] + red[1] + red[2] + red[3]) * (1.f / 1024.f);
  __syncthreads();
  const float d0 = s0 - mu, d1 = s1 - mu, d2 = s2 - mu, d3 = s3 - mu;
  float vs = d0 * d0 + d1 * d1 + d2 * d2 + d3 * d3;
#pragma unroll
  for (int o = 32; o; o >>= 1) vs += __shfl_xor(vs, o);
  if ((tid & 63) == 0) red[tid >> 6] = vs;
  __syncthreads();
  const float var = (red[0] + red[1] + red[2] + red[3]) * (1.f / 1024.f);
  const float rs = rsqrtf(var + 1e-5f);
  float4 vg = *(const float4*)(g + tid * 4);
  float4 ve = *(const float4*)(be + tid * 4);
  const float y0 = d0 * rs * vg.x + ve.x, y1 = d1 * rs * vg.y + ve.y;
  const float y2 = d2 * rs * vg.z + ve.z, y3 = d3 * rs * vg.w + ve.w;
  if (of) { float4 y; y.x = y0; y.y = y1; y.z = y2; y.w = y3; *(float4*)(of + base) = y; }
  if (ob) { u16x4 o; o[0] = f2bf(y0); o[1] = f2bf(y1); o[2] = f2bf(y2); o[3] = f2bf(y3);
            *(u16x4*)(ob + base) = o; }
}

extern "C" void kernel_launch(void* const* d_in, const int* in_sizes, int n_in,
                              void* d_out, int out_size, void* d_ws, size_t ws_size,
                              hipStream_t stream) {
  const float* src = (const float*)d_in[0];
  const int* mask = (const int*)d_in[1];
  const float* Wq = (const float*)d_in[2];
  const float* Wk = (const float*)d_in[3];
  const float* Wv = (const float*)d_in[4];
  const float* Wo = (const float*)d_in[5];
  const float* bo = (const float*)d_in[6];
  const float* g1 = (const float*)d_in[7];
  const float* be1 = (const float*)d_in[8];
  const float* W1 = (const float*)d_in[9];
  const float* b1 = (const float*)d_in[10];
  const float* W2 = (const float*)d_in[11];
  const float* b2 = (const float*)d_in[12];
  const float* g2 = (const float*)d_in[13];
  const float* be2 = (const float*)d_in[14];
  float* outp = (float*)d_out;
  (void)in_sizes; (void)n_in; (void)out_size; (void)ws_size;

  char* ws = (char*)d_ws;
  size_t off = 0;
  auto take = [&](size_t bytes) -> char* {
    char* p = ws + off;
    off = (off + bytes + 255) & ~(size_t)255;
    return p;
  };
  u16* srcb  = (u16*)take((size_t)BS * Dd * 2);
  u16* wqkvt = (u16*)take((size_t)3 * Dd * Dd * 2);
  u16* wot   = (u16*)take((size_t)Dd * Dd * 2);
  u16* w1t   = (u16*)take((size_t)Dd * DFF * 2);
  u16* w2t   = (u16*)take((size_t)DFF * Dd * 2);
  char* qkvr = take((size_t)BS * 3 * Dd * 2);
  u16* qkvb  = (u16*)qkvr;
  float* Cf  = (float*)qkvr;
  u16* attnb = (u16*)take((size_t)BS * Dd * 2);
  float* xf  = (float*)take((size_t)BS * Dd * 4);
  u16* hb    = (u16*)take((size_t)BS * DFF * 2);
  int* flags = (int*)take(256);

  cast_src_k<<<2048, 256, 0, stream>>>(src, srcb, BS * Dd);
  transpose_cast<<<dim3(32, 32), 256, 0, stream>>>(Wq, wqkvt,                Dd, Dd);
  transpose_cast<<<dim3(32, 32), 256, 0, stream>>>(Wk, wqkvt + Dd * Dd,      Dd, Dd);
  transpose_cast<<<dim3(32, 32), 256, 0, stream>>>(Wv, wqkvt + 2 * Dd * Dd,  Dd, Dd);
  transpose_cast<<<dim3(32, 32), 256, 0, stream>>>(Wo, wot, Dd, Dd);
  transpose_cast<<<dim3(128, 32), 256, 0, stream>>>(W1, w1t, Dd, DFF);
  transpose_cast<<<dim3(32, 128), 256, 0, stream>>>(W2, w2t, DFF, Dd);
  mask_init_k<<<1, 64, 0, stream>>>(flags);
  mask_check_k<<<2048, 256, 0, stream>>>(mask, flags, Bb * Ss * Ss);

  // QKV projection via 8-phase 256^2 (Q pre-scaled 0.125)
  gemm8p<3><<<dim3(3 * Dd / 256, BS / 256), 512, 0, stream>>>(srcb, wqkvt, nullptr, qkvb,
                                                              BS, 3 * Dd, Dd);
  attn_fwd<<<Bb * Hh * (Ss / 64), 256, 0, stream>>>(qkvb, mask, flags, attnb);
  gemm_bt<0><<<dim3(Dd / 128, BS / 128), 256, 0, stream>>>(attnb, wot, nullptr, Cf,
                                                           BS, Dd, Dd);
  ln_fuse<<<BS, 256, 0, stream>>>(src, Cf, bo, g1, be1, xf, attnb);
  // h = relu(x @ W1 + b1) via 8-phase 256^2
  gemm8p<2><<<dim3(DFF / 256, BS / 256), 512, 0, stream>>>(attnb, w1t, b1, hb,
                                                           BS, DFF, Dd);
  gemm_bt<0><<<dim3(Dd / 128, BS / 128), 256, 0, stream>>>(hb, w2t, nullptr, Cf,
                                                           BS, Dd, DFF);
  ln_fuse<<<BS, 256, 0, stream>>>(xf, Cf, b2, g2, be2, outp, nullptr);
}